// Round 4
// baseline (250.624 us; speedup 1.0000x reference)
//
#include <hip/hip_runtime.h>

#define NB 1024
#define NP 8192
#define F_PER_BATCH (NP * 3)   // 24576 floats per batch

// ---------------- Pass 1: per-batch sums: sum(p), sum(q), sum(p q^T) ----------------
__global__ __launch_bounds__(256) void cov_kernel(const float* __restrict__ P,
                                                  const float* __restrict__ Q,
                                                  float* __restrict__ sums) {
    const int b = blockIdx.x;
    const int t = threadIdx.x;
    const float* pB = P + (size_t)b * F_PER_BATCH;
    const float* qB = Q + (size_t)b * F_PER_BATCH;

    float sp0=0,sp1=0,sp2=0, sq0=0,sq1=0,sq2=0;
    float s00=0,s01=0,s02=0,s10=0,s11=0,s12=0,s20=0,s21=0,s22=0;

    // 4 points per group = 3 float4 per operand; 2048 groups per batch
    for (int g = t; g < NP/4; g += 256) {
        const float4* p4 = reinterpret_cast<const float4*>(pB) + (size_t)g*3;
        const float4* q4 = reinterpret_cast<const float4*>(qB) + (size_t)g*3;
        float4 pa = p4[0], pb = p4[1], pc = p4[2];
        float4 qa = q4[0], qb = q4[1], qc = q4[2];
        #define ACC(px,py,pz,qx,qy,qz) do { \
            sp0+=(px); sp1+=(py); sp2+=(pz); \
            sq0+=(qx); sq1+=(qy); sq2+=(qz); \
            s00=fmaf((px),(qx),s00); s01=fmaf((px),(qy),s01); s02=fmaf((px),(qz),s02); \
            s10=fmaf((py),(qx),s10); s11=fmaf((py),(qy),s11); s12=fmaf((py),(qz),s12); \
            s20=fmaf((pz),(qx),s20); s21=fmaf((pz),(qy),s21); s22=fmaf((pz),(qz),s22); \
        } while(0)
        ACC(pa.x,pa.y,pa.z, qa.x,qa.y,qa.z);
        ACC(pa.w,pb.x,pb.y, qa.w,qb.x,qb.y);
        ACC(pb.z,pb.w,pc.x, qb.z,qb.w,qc.x);
        ACC(pc.y,pc.z,pc.w, qc.y,qc.z,qc.w);
        #undef ACC
    }

    float vals[15] = {sp0,sp1,sp2,sq0,sq1,sq2,s00,s01,s02,s10,s11,s12,s20,s21,s22};
    #pragma unroll
    for (int i = 0; i < 15; ++i) {
        float v = vals[i];
        v += __shfl_down(v, 32, 64);
        v += __shfl_down(v, 16, 64);
        v += __shfl_down(v, 8, 64);
        v += __shfl_down(v, 4, 64);
        v += __shfl_down(v, 2, 64);
        v += __shfl_down(v, 1, 64);
        vals[i] = v;
    }
    __shared__ float red[4][15];
    const int wave = t >> 6, lane = t & 63;
    if (lane == 0) {
        #pragma unroll
        for (int i = 0; i < 15; ++i) red[wave][i] = vals[i];
    }
    __syncthreads();
    if (t < 15) {
        sums[b*16 + t] = red[0][t] + red[1][t] + red[2][t] + red[3][t];
    }
}

// ---------------- Pass 2: per-batch Kabsch via Horn quaternion method ----------------
// Maximize sum p'.(R(q) q') = q^T K q over unit quaternions q=(w,x,y,z), with
// M = sum p' q'^T. Derived coefficients (verified against R(q) expansion):
//   K00=trM              K01=M21-M12   K02=M02-M20   K03=M10-M01
//   K11=M00-M11-M22      K12=M01+M10   K13=M02+M20
//   K22=M11-M00-M22      K23=M12+M21
//   K33=M22-M00-M11
// Dominant eigenvector of K is the Kabsch quaternion (equals SVD rotation with
// the sign(det) correction). Solve via repeated matrix squaring of the PSD
// shifted matrix S=K+2|A|_F I: 30 squarings -> gap ratio r^(2^30), converges
// even when the eigen-gap (=2*(sigma2-sigma3)) is tiny. S -> rank-1 projector q q^T.
__global__ void kabsch_kernel(const float* __restrict__ sums, float* __restrict__ RT) {
    const int b = blockIdx.x * blockDim.x + threadIdx.x;
    if (b >= NB) return;
    const float* s = sums + b*16;
    const float invN = 1.0f / (float)NP;
    const float sp[3] = {s[0], s[1], s[2]};
    const float sq[3] = {s[3], s[4], s[5]};
    float M[3][3];
    #pragma unroll
    for (int i = 0; i < 3; ++i)
        #pragma unroll
        for (int j = 0; j < 3; ++j)
            M[i][j] = s[6 + 3*i + j] - sp[i]*sq[j]*invN;

    float fro2 = 0.0f;
    #pragma unroll
    for (int i = 0; i < 3; ++i)
        #pragma unroll
        for (int j = 0; j < 3; ++j)
            fro2 = fmaf(M[i][j], M[i][j], fro2);
    const float shift = 2.0f * sqrtf(fro2) + 1e-30f;  // > |lambda_min|, makes K PSD

    float S[4][4];
    const float trM = M[0][0] + M[1][1] + M[2][2];
    S[0][0] = trM + shift;
    S[0][1] = M[2][1] - M[1][2];
    S[0][2] = M[0][2] - M[2][0];
    S[0][3] = M[1][0] - M[0][1];
    S[1][1] = M[0][0] - M[1][1] - M[2][2] + shift;
    S[1][2] = M[0][1] + M[1][0];
    S[1][3] = M[0][2] + M[2][0];
    S[2][2] = M[1][1] - M[0][0] - M[2][2] + shift;
    S[2][3] = M[1][2] + M[2][1];
    S[3][3] = M[2][2] - M[0][0] - M[1][1] + shift;
    S[1][0]=S[0][1]; S[2][0]=S[0][2]; S[3][0]=S[0][3];
    S[2][1]=S[1][2]; S[3][1]=S[1][3]; S[3][2]=S[2][3];

    // normalize so trace=1, then square 30 times (renormalizing each step)
    {
        float tr = S[0][0]+S[1][1]+S[2][2]+S[3][3];
        float inv = 1.0f / tr;
        #pragma unroll
        for (int i = 0; i < 4; ++i)
            #pragma unroll
            for (int j = 0; j < 4; ++j) S[i][j] *= inv;
    }
    #pragma unroll 1
    for (int it = 0; it < 30; ++it) {
        float T[4][4];
        #pragma unroll
        for (int i = 0; i < 4; ++i)
            #pragma unroll
            for (int j = 0; j < 4; ++j) {
                float a = 0.0f;
                #pragma unroll
                for (int k = 0; k < 4; ++k) a = fmaf(S[i][k], S[k][j], a);
                T[i][j] = a;
            }
        float tr = T[0][0]+T[1][1]+T[2][2]+T[3][3];
        float inv = 1.0f / tr;   // trace(S^2) in [trace(S)^2/4, trace(S)^2] -> no under/overflow
        #pragma unroll
        for (int i = 0; i < 4; ++i)
            #pragma unroll
            for (int j = 0; j < 4; ++j) S[i][j] = T[i][j] * inv;
    }

    // S ~= q q^T (trace 1). Take the column with the largest diagonal entry.
    int c = 0;
    float best = S[0][0];
    if (S[1][1] > best) { best = S[1][1]; c = 1; }
    if (S[2][2] > best) { best = S[2][2]; c = 2; }
    if (S[3][3] > best) { best = S[3][3]; c = 3; }
    const float qn = rsqrtf(fmaxf(best, 1e-30f));
    const float w = S[0][c]*qn, x = S[1][c]*qn, y = S[2][c]*qn, z = S[3][c]*qn;

    const float R00 = 1.0f-2.0f*(y*y+z*z), R01 = 2.0f*(x*y-w*z), R02 = 2.0f*(x*z+w*y);
    const float R10 = 2.0f*(x*y+w*z), R11 = 1.0f-2.0f*(x*x+z*z), R12 = 2.0f*(y*z-w*x);
    const float R20 = 2.0f*(x*z-w*y), R21 = 2.0f*(y*z+w*x), R22 = 1.0f-2.0f*(x*x+y*y);

    const float pm0=sp[0]*invN, pm1=sp[1]*invN, pm2=sp[2]*invN;
    const float cm0=sq[0]*invN, cm1=sq[1]*invN, cm2=sq[2]*invN;
    const float t0 = pm0 - (R00*cm0 + R01*cm1 + R02*cm2);
    const float t1 = pm1 - (R10*cm0 + R11*cm1 + R12*cm2);
    const float t2 = pm2 - (R20*cm0 + R21*cm1 + R22*cm2);

    float* rt = RT + b*12;
    rt[0]=R00; rt[1]=R01; rt[2]=R02;
    rt[3]=R10; rt[4]=R11; rt[5]=R12;
    rt[6]=R20; rt[7]=R21; rt[8]=R22;
    rt[9]=t0; rt[10]=t1; rt[11]=t2;
}

// ---------------- Pass 3: distances + threshold counts -> gdt_ts ----------------
__global__ __launch_bounds__(256) void gdt_kernel(const float* __restrict__ P,
                                                  const float* __restrict__ Q,
                                                  const float* __restrict__ RT,
                                                  float* __restrict__ out) {
    const int b = blockIdx.x;
    const int t = threadIdx.x;
    const float* pB = P + (size_t)b * F_PER_BATCH;
    const float* qB = Q + (size_t)b * F_PER_BATCH;
    const float* rt = RT + b*12;
    const float R00=rt[0],R01=rt[1],R02=rt[2],
                R10=rt[3],R11=rt[4],R12=rt[5],
                R20=rt[6],R21=rt[7],R22=rt[8],
                t0=rt[9], t1=rt[10], t2=rt[11];

    int c0=0,c1=0,c2=0,c3=0;
    for (int g = t; g < NP/4; g += 256) {
        const float4* p4 = reinterpret_cast<const float4*>(pB) + (size_t)g*3;
        const float4* q4 = reinterpret_cast<const float4*>(qB) + (size_t)g*3;
        float4 pa = p4[0], pb = p4[1], pc = p4[2];
        float4 qa = q4[0], qb = q4[1], qc = q4[2];
        #define PT(px,py,pz,qx,qy,qz) do { \
            float dx = fmaf(R00,(qx), fmaf(R01,(qy), fmaf(R02,(qz), t0))) - (px); \
            float dy = fmaf(R10,(qx), fmaf(R11,(qy), fmaf(R12,(qz), t1))) - (py); \
            float dz = fmaf(R20,(qx), fmaf(R21,(qy), fmaf(R22,(qz), t2))) - (pz); \
            float d2 = fmaf(dx,dx, fmaf(dy,dy, dz*dz)); \
            c0 += (d2 < 1.0f); c1 += (d2 < 4.0f); c2 += (d2 < 16.0f); c3 += (d2 < 64.0f); \
        } while(0)
        PT(pa.x,pa.y,pa.z, qa.x,qa.y,qa.z);
        PT(pa.w,pb.x,pb.y, qa.w,qb.x,qb.y);
        PT(pb.z,pb.w,pc.x, qb.z,qb.w,qc.x);
        PT(pc.y,pc.z,pc.w, qc.y,qc.z,qc.w);
        #undef PT
    }

    int c = c0 + c1 + c2 + c3;
    c += __shfl_down(c, 32, 64);
    c += __shfl_down(c, 16, 64);
    c += __shfl_down(c, 8, 64);
    c += __shfl_down(c, 4, 64);
    c += __shfl_down(c, 2, 64);
    c += __shfl_down(c, 1, 64);
    __shared__ int red[4];
    if ((t & 63) == 0) red[t >> 6] = c;
    __syncthreads();
    if (t == 0) {
        const int total = red[0] + red[1] + red[2] + red[3];
        out[b] = (float)total * (1.0f / (4.0f * (float)NP));
    }
}

extern "C" void kernel_launch(void* const* d_in, const int* in_sizes, int n_in,
                              void* d_out, int out_size, void* d_ws, size_t ws_size,
                              hipStream_t stream) {
    const float* P = (const float*)d_in[0];   // coords_pred [B,N,3]
    const float* Q = (const float*)d_in[1];   // coords      [B,N,3]
    float* out = (float*)d_out;               // gdt_ts [B]

    float* sums = (float*)d_ws;                                        // 1024*16 floats = 64 KB
    float* RT   = (float*)((char*)d_ws + (size_t)NB*16*sizeof(float)); // 1024*12 floats = 48 KB

    cov_kernel<<<NB, 256, 0, stream>>>(P, Q, sums);
    kabsch_kernel<<<NB/256, 256, 0, stream>>>(sums, RT);
    gdt_kernel<<<NB, 256, 0, stream>>>(P, Q, RT, out);
}